// Round 4
// baseline (506.214 us; speedup 1.0000x reference)
//
#include <hip/hip_runtime.h>
#include <hip/hip_bf16.h>
#include <math.h>

// ---------------------------------------------------------------------------
// GAT 3-layer forward.
// R5: layers 1-2 h in FP16 (gather bytes halved; fabric-bound confirmed).
// R6: layer-3 h FP16; als/ald fused into GEMM epilogue.
// R8: GEMM inputs pre-split into PACKED bf16 hi/lo planes by producers
//     (asplit for x; aggregate epilogue for h1/h2). Packed tile layout
//     [K/32][M/16][4q][16r][8k] -> each 128x32 tile is one contiguous 8KB
//     blob, staged reg->LDS conflict-free, frag reads = lane*16 linear.
//     Deletes all per-K-step split VALU from the GEMM; LDS 40->33KB,
//     VGPR down -> ~4 blocks/CU. Bit-identical numerics to R6.
// ---------------------------------------------------------------------------

#define NEG_SLOPE 0.2f
#define EPS_SM 1e-16f

typedef __bf16 bf16x8 __attribute__((ext_vector_type(8)));
typedef float f32x4 __attribute__((ext_vector_type(4)));
typedef _Float16 half4 __attribute__((ext_vector_type(4)));
typedef _Float16 half2v __attribute__((ext_vector_type(2)));

__device__ __forceinline__ float wave_allred_sum(float v) {
#pragma unroll
    for (int o = 32; o > 0; o >>= 1) v += __shfl_xor(v, o, 64);
    return v;
}
__device__ __forceinline__ float wave_allred_max(float v) {
#pragma unroll
    for (int o = 32; o > 0; o >>= 1) v = fmaxf(v, __shfl_xor(v, o, 64));
    return v;
}
__device__ __forceinline__ float4 lrelu4(float4 v) {
    v.x = (v.x < 0.f) ? NEG_SLOPE * v.x : v.x;
    v.y = (v.y < 0.f) ? NEG_SLOPE * v.y : v.y;
    v.z = (v.z < 0.f) ? NEG_SLOPE * v.z : v.z;
    v.w = (v.w < 0.f) ? NEG_SLOPE * v.w : v.w;
    return v;
}

// ---------------- CSR build ----------------
__global__ void hist_kernel(const int* __restrict__ ei, int E, int N,
                            int* __restrict__ cnt) {
    int e = blockIdx.x * 256 + threadIdx.x;
    int ET = E + N;
    if (e >= ET) return;
    int dst = (e < E) ? ei[E + e] : (e - E);
    atomicAdd(&cnt[dst], 1);
}

__global__ void scan_block(const int* __restrict__ cnt, int n_cnt,
                           int* __restrict__ offs, int n_off,
                           int* __restrict__ bsums) {
    __shared__ int buf[1024];
    int gid = blockIdx.x * 1024 + threadIdx.x;
    int v = (gid < n_cnt) ? cnt[gid] : 0;
    buf[threadIdx.x] = v;
    __syncthreads();
#pragma unroll
    for (int off = 1; off < 1024; off <<= 1) {
        int t = (threadIdx.x >= off) ? buf[threadIdx.x - off] : 0;
        __syncthreads();
        buf[threadIdx.x] += t;
        __syncthreads();
    }
    if (gid < n_off) offs[gid] = buf[threadIdx.x] - v;
    if (threadIdx.x == 1023) bsums[blockIdx.x] = buf[1023];
}

__global__ void scan_sums(int* __restrict__ bsums, int nb) {
    if (threadIdx.x == 0 && blockIdx.x == 0) {
        int run = 0;
        for (int i = 0; i < nb; ++i) { int t = bsums[i]; bsums[i] = run; run += t; }
    }
}

__global__ void scan_add(int* __restrict__ offs, int n_off,
                         const int* __restrict__ bsums) {
    int gid = blockIdx.x * 1024 + threadIdx.x;
    if (gid < n_off) offs[gid] += bsums[blockIdx.x];
}

__global__ void fill_csr(const int* __restrict__ ei, int E, int N,
                         const int* __restrict__ offs, int* __restrict__ fil,
                         int* __restrict__ csr) {
    int e = blockIdx.x * 256 + threadIdx.x;
    int ET = E + N;
    if (e >= ET) return;
    int src, dst;
    if (e < E) { src = ei[e]; dst = ei[E + e]; }
    else       { src = dst = e - E; }
    int pos = offs[dst] + atomicAdd(&fil[dst], 1);
    csr[pos] = src;
}

// ---------------- W split into packed planes [K/32][N/16][4q][16r][8k] -----
__global__ void wsplit_packed(const float* __restrict__ W, int K, int N,
                              unsigned short* __restrict__ Ph,
                              unsigned short* __restrict__ Pl) {
    int idx = blockIdx.x * 256 + threadIdx.x;  // over N*K
    if (idx >= N * K) return;
    int n = idx / K, k = idx - n * K;
    float v = W[(size_t)k * N + n];
    unsigned u = __float_as_uint(v);
    float d = v - __uint_as_float(u & 0xffff0000u);
    int k0 = k >> 5, q = (k & 31) >> 3, kr = k & 7;
    int nb = n >> 4, nr = n & 15;
    size_t off = (((size_t)k0 * (N >> 4) + nb) * 4 + q) * 128 + nr * 8 + kr;
    Ph[off] = (unsigned short)(u >> 16);
    Pl[off] = (unsigned short)(__float_as_uint(d) >> 16);
}

// ---------------- x split into packed planes (layer-1 A), pad zero-filled --
__global__ void asplit_packed(const float* __restrict__ A, int M, int Mp,
                              unsigned short* __restrict__ Ph,
                              unsigned short* __restrict__ Pl) {
    int idx = blockIdx.x * 256 + threadIdx.x;  // over Mp*32 (8-elem k-groups)
    if (idx >= Mp * 32) return;
    int m = idx >> 5, g = idx & 31;            // g = k/8
    float vf[8];
    if (m < M) {
        const float4* ap = (const float4*)(A + (size_t)m * 256 + g * 8);
        float4 v0 = ap[0], v1 = ap[1];
        vf[0] = v0.x; vf[1] = v0.y; vf[2] = v0.z; vf[3] = v0.w;
        vf[4] = v1.x; vf[5] = v1.y; vf[6] = v1.z; vf[7] = v1.w;
    } else {
#pragma unroll
        for (int i = 0; i < 8; ++i) vf[i] = 0.f;
    }
    unsigned hi[4], lo[4];
#pragma unroll
    for (int i = 0; i < 4; ++i) {
        unsigned u0 = __float_as_uint(vf[2 * i]);
        unsigned u1 = __float_as_uint(vf[2 * i + 1]);
        hi[i] = (u0 >> 16) | (u1 & 0xffff0000u);
        float d0 = vf[2 * i]     - __uint_as_float(u0 & 0xffff0000u);
        float d1 = vf[2 * i + 1] - __uint_as_float(u1 & 0xffff0000u);
        lo[i] = (__float_as_uint(d0) >> 16) | (__float_as_uint(d1) & 0xffff0000u);
    }
    int k0 = g >> 2, q = g & 3;
    size_t off = (((size_t)k0 * (Mp >> 4) + (m >> 4)) * 4 + q) * 128 + (m & 15) * 8;
    *(uint4*)&Ph[off] = make_uint4(hi[0], hi[1], hi[2], hi[3]);
    *(uint4*)&Pl[off] = make_uint4(lo[0], lo[1], lo[2], lo[3]);
}

// ---------------- packed-plane MFMA GEMM: C[M,N] = A[M,K] @ B[K,N] ---------
// A,B as packed bf16 hi/lo planes. BM=128 BN=128 BK=32; 4 waves 2x2.
// ALMODE: 0=none; 1=per-wave head sum (H=4); 2=block LDS reduce (H=1).
template <typename OutT, int ALMODE>
__global__ __launch_bounds__(256) void gemm_packed(
    const unsigned short* __restrict__ Aph, const unsigned short* __restrict__ Apl,
    const unsigned short* __restrict__ Bph, const unsigned short* __restrict__ Bpl,
    OutT* __restrict__ C,
    const float* __restrict__ a_s, const float* __restrict__ a_d,
    float* __restrict__ als, float* __restrict__ ald,
    int M, int mtiles, int N, int K) {
    __shared__ unsigned short Ah[4096], Al[4096], Bh[4096], Bl[4096];  // 32 KB
    __shared__ float s_als[128], s_ald[128];
    const int bm = blockIdx.y * 128, bn = blockIdx.x * 128;
    const int tid = threadIdx.x;
    const int w = tid >> 6, lane = tid & 63;
    const int wm = (w >> 1) * 64, wn = (w & 1) * 64;
    const int l16 = lane & 15, q = lane >> 4;
    const int ntiles = N >> 4;

    f32x4 acc[4][4];
#pragma unroll
    for (int i = 0; i < 4; ++i)
#pragma unroll
        for (int j = 0; j < 4; ++j) acc[i][j] = (f32x4){0.f, 0.f, 0.f, 0.f};

    for (int kb = 0; kb < (K >> 5); ++kb) {
        const size_t abase = ((size_t)kb * mtiles + (bm >> 4)) * 512;
        const size_t bbase = ((size_t)kb * ntiles + (bn >> 4)) * 512;
        // stage: contiguous 8KB per plane, 2x uint4 per thread
#pragma unroll
        for (int c = 0; c < 2; ++c) {
            int slot = (tid + c * 256) * 8;
            *(uint4*)&Ah[slot] = *(const uint4*)&Aph[abase + slot];
            *(uint4*)&Al[slot] = *(const uint4*)&Apl[abase + slot];
            *(uint4*)&Bh[slot] = *(const uint4*)&Bph[bbase + slot];
            *(uint4*)&Bl[slot] = *(const uint4*)&Bpl[bbase + slot];
        }
        __syncthreads();
        bf16x8 aH[4], aL[4], bH[4], bL[4];
#pragma unroll
        for (int t = 0; t < 4; ++t) {
            int ao = (((wm >> 4) + t) * 64 + q * 16 + l16) * 8;
            int bo = (((wn >> 4) + t) * 64 + q * 16 + l16) * 8;
            aH[t] = *(const bf16x8*)&Ah[ao];
            aL[t] = *(const bf16x8*)&Al[ao];
            bH[t] = *(const bf16x8*)&Bh[bo];
            bL[t] = *(const bf16x8*)&Bl[bo];
        }
#pragma unroll
        for (int i = 0; i < 4; ++i)
#pragma unroll
            for (int j = 0; j < 4; ++j) {
                acc[i][j] = __builtin_amdgcn_mfma_f32_16x16x32_bf16(
                    aH[i], bH[j], acc[i][j], 0, 0, 0);
                acc[i][j] = __builtin_amdgcn_mfma_f32_16x16x32_bf16(
                    aH[i], bL[j], acc[i][j], 0, 0, 0);
                acc[i][j] = __builtin_amdgcn_mfma_f32_16x16x32_bf16(
                    aL[i], bH[j], acc[i][j], 0, 0, 0);
            }
        __syncthreads();
    }

    if constexpr (ALMODE == 2) {
        if (tid < 128) { s_als[tid] = 0.f; s_ald[tid] = 0.f; }
        __syncthreads();
    }
    // epilogue: C/D layout col = lane&15, row = q*4 + reg
#pragma unroll
    for (int i = 0; i < 4; ++i) {
#pragma unroll
        for (int r = 0; r < 4; ++r) {
            int row = bm + wm + i * 16 + q * 4 + r;
            float c0 = acc[i][0][r], c1 = acc[i][1][r];
            float c2 = acc[i][2][r], c3 = acc[i][3][r];
            if (row < M) {
                OutT* cp = C + (size_t)row * N + bn + wn + l16;
                cp[0]  = (OutT)c0;
                cp[16] = (OutT)c1;
                cp[32] = (OutT)c2;
                cp[48] = (OutT)c3;
            }
            if constexpr (ALMODE != 0) {
                const int cg = bn + wn + l16;
                float ps = c0 * a_s[cg] + c1 * a_s[cg + 16] +
                           c2 * a_s[cg + 32] + c3 * a_s[cg + 48];
                float pd = c0 * a_d[cg] + c1 * a_d[cg + 16] +
                           c2 * a_d[cg + 32] + c3 * a_d[cg + 48];
#pragma unroll
                for (int o = 1; o < 16; o <<= 1) {
                    ps += __shfl_xor(ps, o, 64);
                    pd += __shfl_xor(pd, o, 64);
                }
                if constexpr (ALMODE == 1) {
                    if (l16 == 0 && row < M) {
                        const int head = (bn + wn) >> 6;
                        als[row * 4 + head] = ps;
                        ald[row * 4 + head] = pd;
                    }
                } else {
                    if (l16 == 0) {
                        atomicAdd(&s_als[wm + i * 16 + q * 4 + r], ps);
                        atomicAdd(&s_ald[wm + i * 16 + q * 4 + r], pd);
                    }
                }
            }
        }
    }
    if constexpr (ALMODE == 2) {
        __syncthreads();
        if (tid < 128) {
            int row = bm + tid;
            if (row < M) { als[row] = s_als[tid]; ald[row] = s_ald[tid]; }
        }
    }
}

// ---------------- aggregation H=4 C=64: fp16 h gather, packed-plane out ----
template <bool ACT>
__global__ __launch_bounds__(256) void aggregate_h4_f16(
    const _Float16* __restrict__ h, const float4* __restrict__ als4,
    const float4* __restrict__ ald4, const int* __restrict__ offs,
    const int* __restrict__ csr, const float* __restrict__ bias,
    unsigned short* __restrict__ Ph, unsigned short* __restrict__ Pl,
    int mtiles, int Nn) {
    const int tid = threadIdx.x;
    const int w = tid >> 6;
    const int l = tid & 63;
    const int n = blockIdx.x * 4 + w;
    __shared__ float s_alpha[4][64][4];
    __shared__ int s_src[4][64];
    if (n >= Nn) return;

    const int base = offs[n];
    const int deg = offs[n + 1] - base;
    const float4 adv = ald4[n];

    const bool has0 = (l < deg);
    int src0 = 0;
    float4 sc0 = make_float4(-1e30f, -1e30f, -1e30f, -1e30f);
    if (has0) {
        src0 = csr[base + l];
        float4 a = als4[src0];
        sc0 = lrelu4(make_float4(a.x + adv.x, a.y + adv.y, a.z + adv.z, a.w + adv.w));
    }
    float4 m = sc0;
    for (int i = l + 64; i < deg; i += 64) {
        int s = csr[base + i];
        float4 a = als4[s];
        float4 sc = lrelu4(make_float4(a.x + adv.x, a.y + adv.y, a.z + adv.z, a.w + adv.w));
        m.x = fmaxf(m.x, sc.x); m.y = fmaxf(m.y, sc.y);
        m.z = fmaxf(m.z, sc.z); m.w = fmaxf(m.w, sc.w);
    }
    m.x = wave_allred_max(m.x); m.y = wave_allred_max(m.y);
    m.z = wave_allred_max(m.z); m.w = wave_allred_max(m.w);

    float4 ssum = make_float4(0.f, 0.f, 0.f, 0.f);
    if (has0) {
        float4 ex = make_float4(__expf(sc0.x - m.x), __expf(sc0.y - m.y),
                                __expf(sc0.z - m.z), __expf(sc0.w - m.w));
        *(float4*)&s_alpha[w][l][0] = ex;
        s_src[w][l] = src0;
        ssum = ex;
    }
    for (int i = l + 64; i < deg; i += 64) {
        int s = csr[base + i];
        float4 a = als4[s];
        float4 sc = lrelu4(make_float4(a.x + adv.x, a.y + adv.y, a.z + adv.z, a.w + adv.w));
        ssum.x += __expf(sc.x - m.x); ssum.y += __expf(sc.y - m.y);
        ssum.z += __expf(sc.z - m.z); ssum.w += __expf(sc.w - m.w);
    }
    ssum.x = wave_allred_sum(ssum.x); ssum.y = wave_allred_sum(ssum.y);
    ssum.z = wave_allred_sum(ssum.z); ssum.w = wave_allred_sum(ssum.w);

    const int head = l >> 4;
    float rc;
    {
        float d = (head == 0) ? ssum.x : (head == 1) ? ssum.y
                 : (head == 2) ? ssum.z : ssum.w;
        rc = 1.f / (d + EPS_SM);
    }

    float4 acc = make_float4(0.f, 0.f, 0.f, 0.f);
    for (int c0 = 0; c0 < deg; c0 += 64) {
        const int cl = min(64, deg - c0);
        if (c0 > 0) {
            if (l < cl) {
                int s = csr[base + c0 + l];
                float4 a = als4[s];
                float4 sc = lrelu4(make_float4(a.x + adv.x, a.y + adv.y,
                                               a.z + adv.z, a.w + adv.w));
                s_alpha[w][l][0] = __expf(sc.x - m.x);
                s_alpha[w][l][1] = __expf(sc.y - m.y);
                s_alpha[w][l][2] = __expf(sc.z - m.z);
                s_alpha[w][l][3] = __expf(sc.w - m.w);
                s_src[w][l] = s;
            }
        }
        int e = 0;
        for (; e + 4 <= cl; e += 4) {
            int s0 = s_src[w][e + 0], s1 = s_src[w][e + 1];
            int s2 = s_src[w][e + 2], s3 = s_src[w][e + 3];
            float a0 = s_alpha[w][e + 0][head];
            float a1 = s_alpha[w][e + 1][head];
            float a2 = s_alpha[w][e + 2][head];
            float a3 = s_alpha[w][e + 3][head];
            half4 hv0 = *(const half4*)(h + (size_t)s0 * 256 + l * 4);
            half4 hv1 = *(const half4*)(h + (size_t)s1 * 256 + l * 4);
            half4 hv2 = *(const half4*)(h + (size_t)s2 * 256 + l * 4);
            half4 hv3 = *(const half4*)(h + (size_t)s3 * 256 + l * 4);
            acc.x = fmaf(a0, (float)hv0[0], acc.x);
            acc.y = fmaf(a0, (float)hv0[1], acc.y);
            acc.z = fmaf(a0, (float)hv0[2], acc.z);
            acc.w = fmaf(a0, (float)hv0[3], acc.w);
            acc.x = fmaf(a1, (float)hv1[0], acc.x);
            acc.y = fmaf(a1, (float)hv1[1], acc.y);
            acc.z = fmaf(a1, (float)hv1[2], acc.z);
            acc.w = fmaf(a1, (float)hv1[3], acc.w);
            acc.x = fmaf(a2, (float)hv2[0], acc.x);
            acc.y = fmaf(a2, (float)hv2[1], acc.y);
            acc.z = fmaf(a2, (float)hv2[2], acc.z);
            acc.w = fmaf(a2, (float)hv2[3], acc.w);
            acc.x = fmaf(a3, (float)hv3[0], acc.x);
            acc.y = fmaf(a3, (float)hv3[1], acc.y);
            acc.z = fmaf(a3, (float)hv3[2], acc.z);
            acc.w = fmaf(a3, (float)hv3[3], acc.w);
        }
        for (; e < cl; ++e) {
            int s0 = s_src[w][e];
            float a0 = s_alpha[w][e][head];
            half4 hv0 = *(const half4*)(h + (size_t)s0 * 256 + l * 4);
            acc.x = fmaf(a0, (float)hv0[0], acc.x);
            acc.y = fmaf(a0, (float)hv0[1], acc.y);
            acc.z = fmaf(a0, (float)hv0[2], acc.z);
            acc.w = fmaf(a0, (float)hv0[3], acc.w);
        }
    }
    float4 bv = *(const float4*)(bias + l * 4);
    float4 r = make_float4(acc.x * rc + bv.x, acc.y * rc + bv.y,
                           acc.z * rc + bv.z, acc.w * rc + bv.w);
    if (ACT) {
        r.x = (r.x > 0.f) ? r.x : expm1f(r.x);
        r.y = (r.y > 0.f) ? r.y : expm1f(r.y);
        r.z = (r.z > 0.f) ? r.z : expm1f(r.z);
        r.w = (r.w > 0.f) ? r.w : expm1f(r.w);
    }
    // packed-plane hi/lo write (same truncation as the old in-GEMM split)
    unsigned u0 = __float_as_uint(r.x), u1 = __float_as_uint(r.y);
    unsigned u2 = __float_as_uint(r.z), u3 = __float_as_uint(r.w);
    float d0 = r.x - __uint_as_float(u0 & 0xffff0000u);
    float d1 = r.y - __uint_as_float(u1 & 0xffff0000u);
    float d2 = r.z - __uint_as_float(u2 & 0xffff0000u);
    float d3 = r.w - __uint_as_float(u3 & 0xffff0000u);
    uint2 hi = make_uint2((u0 >> 16) | (u1 & 0xffff0000u),
                          (u2 >> 16) | (u3 & 0xffff0000u));
    uint2 lo = make_uint2((__float_as_uint(d0) >> 16) | (__float_as_uint(d1) & 0xffff0000u),
                          (__float_as_uint(d2) >> 16) | (__float_as_uint(d3) & 0xffff0000u));
    const int k0 = l >> 3, qq = (l >> 1) & 3, kr = (l & 1) * 4;
    size_t off = (((size_t)k0 * mtiles + (n >> 4)) * 4 + qq) * 128 + (n & 15) * 8 + kr;
    *(uint2*)&Ph[off] = hi;
    *(uint2*)&Pl[off] = lo;
}

// ---------------- aggregation H=1 C=128 (fp16 h, output layer, f32 out) ----
__global__ __launch_bounds__(256) void aggregate_h1_f16(
    const _Float16* __restrict__ h, const float* __restrict__ als,
    const float* __restrict__ ald, const int* __restrict__ offs,
    const int* __restrict__ csr, const float* __restrict__ bias,
    float* __restrict__ out, int Nn) {
    const int tid = threadIdx.x;
    const int w = tid >> 6;
    const int l = tid & 63;
    const int n = blockIdx.x * 4 + w;
    __shared__ float s_alpha[4][64];
    __shared__ int s_src[4][64];
    if (n >= Nn) return;

    const int base = offs[n];
    const int deg = offs[n + 1] - base;
    const float ad_n = ald[n];

    const bool has0 = (l < deg);
    int src0 = 0;
    float sc0 = -1e30f;
    if (has0) {
        src0 = csr[base + l];
        float sc = als[src0] + ad_n;
        sc0 = (sc < 0.f) ? NEG_SLOPE * sc : sc;
    }
    float m = sc0;
    for (int i = l + 64; i < deg; i += 64) {
        int s = csr[base + i];
        float sc = als[s] + ad_n;
        sc = (sc < 0.f) ? NEG_SLOPE * sc : sc;
        m = fmaxf(m, sc);
    }
    m = wave_allred_max(m);

    float ssum = 0.f;
    if (has0) {
        float ex = __expf(sc0 - m);
        s_alpha[w][l] = ex;
        s_src[w][l] = src0;
        ssum = ex;
    }
    for (int i = l + 64; i < deg; i += 64) {
        int s = csr[base + i];
        float sc = als[s] + ad_n;
        sc = (sc < 0.f) ? NEG_SLOPE * sc : sc;
        ssum += __expf(sc - m);
    }
    ssum = wave_allred_sum(ssum);
    const float rc = 1.f / (ssum + EPS_SM);

    float2 acc = make_float2(0.f, 0.f);
    for (int c0 = 0; c0 < deg; c0 += 64) {
        const int cl = min(64, deg - c0);
        if (c0 > 0) {
            if (l < cl) {
                int s = csr[base + c0 + l];
                float sc = als[s] + ad_n;
                sc = (sc < 0.f) ? NEG_SLOPE * sc : sc;
                s_alpha[w][l] = __expf(sc - m);
                s_src[w][l] = s;
            }
        }
        int e = 0;
        for (; e + 4 <= cl; e += 4) {
            int s0 = s_src[w][e + 0], s1 = s_src[w][e + 1];
            int s2 = s_src[w][e + 2], s3 = s_src[w][e + 3];
            float a0 = s_alpha[w][e + 0], a1 = s_alpha[w][e + 1];
            float a2 = s_alpha[w][e + 2], a3 = s_alpha[w][e + 3];
            half2v v0 = *(const half2v*)(h + (size_t)s0 * 128 + l * 2);
            half2v v1 = *(const half2v*)(h + (size_t)s1 * 128 + l * 2);
            half2v v2 = *(const half2v*)(h + (size_t)s2 * 128 + l * 2);
            half2v v3 = *(const half2v*)(h + (size_t)s3 * 128 + l * 2);
            acc.x = fmaf(a0, (float)v0[0], acc.x); acc.y = fmaf(a0, (float)v0[1], acc.y);
            acc.x = fmaf(a1, (float)v1[0], acc.x); acc.y = fmaf(a1, (float)v1[1], acc.y);
            acc.x = fmaf(a2, (float)v2[0], acc.x); acc.y = fmaf(a2, (float)v2[1], acc.y);
            acc.x = fmaf(a3, (float)v3[0], acc.x); acc.y = fmaf(a3, (float)v3[1], acc.y);
        }
        for (; e < cl; ++e) {
            int s0 = s_src[w][e];
            float a0 = s_alpha[w][e];
            half2v v0 = *(const half2v*)(h + (size_t)s0 * 128 + l * 2);
            acc.x = fmaf(a0, (float)v0[0], acc.x); acc.y = fmaf(a0, (float)v0[1], acc.y);
        }
    }
    float2 r = make_float2(acc.x * rc + bias[l * 2],
                           acc.y * rc + bias[l * 2 + 1]);
    *(float2*)(out + (size_t)n * 128 + l * 2) = r;
}

// ---------------------------------------------------------------------------
extern "C" void kernel_launch(void* const* d_in, const int* in_sizes, int n_in,
                              void* d_out, int out_size, void* d_ws,
                              size_t ws_size, hipStream_t stream) {
    const float* x   = (const float*)d_in[0];
    const int*   ei  = (const int*)d_in[1];
    const float* W1  = (const float*)d_in[2];
    const float* as1 = (const float*)d_in[3];
    const float* ad1 = (const float*)d_in[4];
    const float* b1  = (const float*)d_in[5];
    const float* W2  = (const float*)d_in[6];
    const float* as2 = (const float*)d_in[7];
    const float* ad2 = (const float*)d_in[8];
    const float* b2  = (const float*)d_in[9];
    const float* W3  = (const float*)d_in[10];
    const float* as3 = (const float*)d_in[11];
    const float* ad3 = (const float*)d_in[12];
    const float* b3  = (const float*)d_in[13];

    const int Nn = in_sizes[0] / 256;   // 50000 nodes
    const int E  = in_sizes[1] / 2;     // 800000 edges
    const int ET = E + Nn;

    const int gm = (Nn + 127) / 128;    // 391
    const int Mp = gm * 128;            // 50048 (padded rows)
    const int mtiles = Mp >> 4;         // 3128
    const int ga = (Nn + 3) / 4;        // 12500

    // workspace carve
    char* p = (char*)d_ws;
    _Float16* hbuf = (_Float16*)p; p += (size_t)Nn * 256 * 2;  // fp16 h (gather src)
    unsigned short* Aph = (unsigned short*)p; p += (size_t)Mp * 256 * 2;
    unsigned short* Apl = (unsigned short*)p; p += (size_t)Mp * 256 * 2;
    float* als  = (float*)p; p += (size_t)Nn * 4 * 4;
    float* ald  = (float*)p; p += (size_t)Nn * 4 * 4;
    int* cnt  = (int*)p; p += (size_t)Nn * 4;
    int* fil  = (int*)p; p += (size_t)Nn * 4;
    int* offs = (int*)p; p += (size_t)(Nn + 1) * 4;
    int* bsums = (int*)p; p += 256 * 4;
    int* csr  = (int*)p; p += (size_t)ET * 4;
    p = (char*)(((uintptr_t)p + 15) & ~(uintptr_t)15);
    unsigned short* wt1h = (unsigned short*)p; p += 256 * 256 * 2;
    unsigned short* wt1l = (unsigned short*)p; p += 256 * 256 * 2;
    unsigned short* wt2h = (unsigned short*)p; p += 256 * 256 * 2;
    unsigned short* wt2l = (unsigned short*)p; p += 256 * 256 * 2;
    unsigned short* wt3h = (unsigned short*)p; p += 128 * 256 * 2;
    unsigned short* wt3l = (unsigned short*)p; p += 128 * 256 * 2;

    // --- CSR build + W splits + x split ---
    hipMemsetAsync(cnt, 0, (size_t)2 * Nn * sizeof(int), stream);
    int nbE = (ET + 255) / 256;
    hist_kernel<<<nbE, 256, 0, stream>>>(ei, E, Nn, cnt);
    wsplit_packed<<<(256 * 256 + 255) / 256, 256, 0, stream>>>(W1, 256, 256, wt1h, wt1l);
    wsplit_packed<<<(256 * 256 + 255) / 256, 256, 0, stream>>>(W2, 256, 256, wt2h, wt2l);
    wsplit_packed<<<(128 * 256 + 255) / 256, 256, 0, stream>>>(W3, 256, 128, wt3h, wt3l);
    asplit_packed<<<(Mp * 32 + 255) / 256, 256, 0, stream>>>(x, Nn, Mp, Aph, Apl);
    int nbS = (Nn + 1 + 1023) / 1024;
    scan_block<<<nbS, 1024, 0, stream>>>(cnt, Nn, offs, Nn + 1, bsums);
    scan_sums<<<1, 64, 0, stream>>>(bsums, nbS);
    scan_add<<<nbS, 1024, 0, stream>>>(offs, Nn + 1, bsums);
    fill_csr<<<nbE, 256, 0, stream>>>(ei, E, Nn, offs, fil, csr);

    // --- layer 1: 256 -> 256, H=4, C=64, ELU ---
    gemm_packed<_Float16, 1><<<dim3(2, gm), 256, 0, stream>>>(
        Aph, Apl, wt1h, wt1l, hbuf, as1, ad1, als, ald, Nn, mtiles, 256, 256);
    aggregate_h4_f16<true><<<ga, 256, 0, stream>>>(
        hbuf, (const float4*)als, (const float4*)ald, offs, csr, b1,
        Aph, Apl, mtiles, Nn);

    // --- layer 2: 256 -> 256, H=4, C=64, ELU ---
    gemm_packed<_Float16, 1><<<dim3(2, gm), 256, 0, stream>>>(
        Aph, Apl, wt2h, wt2l, hbuf, as2, ad2, als, ald, Nn, mtiles, 256, 256);
    aggregate_h4_f16<true><<<ga, 256, 0, stream>>>(
        hbuf, (const float4*)als, (const float4*)ald, offs, csr, b2,
        Aph, Apl, mtiles, Nn);

    // --- layer 3: 256 -> 128, H=1, C=128, no act ---
    gemm_packed<_Float16, 2><<<dim3(1, gm), 256, 0, stream>>>(
        Aph, Apl, wt3h, wt3l, hbuf, as3, ad3, als, ald, Nn, mtiles, 128, 256);
    aggregate_h1_f16<<<ga, 256, 0, stream>>>(
        hbuf, als, ald, offs, csr, b3, (float*)d_out, Nn);
}

// Round 5
// 456.828 us; speedup vs baseline: 1.1081x; 1.1081x over previous
//
#include <hip/hip_runtime.h>
#include <math.h>

// ---------------------------------------------------------------------------
// GAT 3-layer forward.
// R5/R6: fp16 h for all gathers (fabric bytes-bound, dur ~ FETCH confirmed).
// R8: packed-plane producer split -> NULL/regression: GEMM not staging-bound.
// R9: all-fp16 datapath. GEMM = mfma_f32_16x16x32_f16, single plane
//     (3x fewer MFMAs than split-bf16, half the A bytes). Node features
//     live in ONE fp16 buffer per stage (GEMM-A == gather source).
//     asplit/wsplit deleted (xcast/wcast trivial). scan_sums parallelized.
//     Accepted risk: fp16 operand rounding, predicted absmax ~1e-3.
// ---------------------------------------------------------------------------

#define NEG_SLOPE 0.2f
#define EPS_SM 1e-16f

typedef _Float16 half8 __attribute__((ext_vector_type(8)));
typedef _Float16 half4v __attribute__((ext_vector_type(4)));
typedef _Float16 half2v __attribute__((ext_vector_type(2)));
typedef float f32x4 __attribute__((ext_vector_type(4)));

__device__ __forceinline__ float wave_allred_sum(float v) {
#pragma unroll
    for (int o = 32; o > 0; o >>= 1) v += __shfl_xor(v, o, 64);
    return v;
}
__device__ __forceinline__ float wave_allred_max(float v) {
#pragma unroll
    for (int o = 32; o > 0; o >>= 1) v = fmaxf(v, __shfl_xor(v, o, 64));
    return v;
}
__device__ __forceinline__ float4 lrelu4(float4 v) {
    v.x = (v.x < 0.f) ? NEG_SLOPE * v.x : v.x;
    v.y = (v.y < 0.f) ? NEG_SLOPE * v.y : v.y;
    v.z = (v.z < 0.f) ? NEG_SLOPE * v.z : v.z;
    v.w = (v.w < 0.f) ? NEG_SLOPE * v.w : v.w;
    return v;
}

// ---------------- CSR build ----------------
__global__ void hist_kernel(const int* __restrict__ ei, int E, int N,
                            int* __restrict__ cnt) {
    int e = blockIdx.x * 256 + threadIdx.x;
    int ET = E + N;
    if (e >= ET) return;
    int dst = (e < E) ? ei[E + e] : (e - E);
    atomicAdd(&cnt[dst], 1);
}

__global__ void scan_block(const int* __restrict__ cnt, int n_cnt,
                           int* __restrict__ offs, int n_off,
                           int* __restrict__ bsums) {
    __shared__ int buf[1024];
    int gid = blockIdx.x * 1024 + threadIdx.x;
    int v = (gid < n_cnt) ? cnt[gid] : 0;
    buf[threadIdx.x] = v;
    __syncthreads();
#pragma unroll
    for (int off = 1; off < 1024; off <<= 1) {
        int t = (threadIdx.x >= off) ? buf[threadIdx.x - off] : 0;
        __syncthreads();
        buf[threadIdx.x] += t;
        __syncthreads();
    }
    if (gid < n_off) offs[gid] = buf[threadIdx.x] - v;
    if (threadIdx.x == 1023) bsums[blockIdx.x] = buf[1023];
}

// parallel exclusive scan of block sums (nb <= 64, one wave)
__global__ void scan_sums(int* __restrict__ bsums, int nb) {
    int l = threadIdx.x;
    int v = (l < nb) ? bsums[l] : 0;
    int s = v;
#pragma unroll
    for (int o = 1; o < 64; o <<= 1) {
        int t = __shfl_up(s, o, 64);
        if (l >= o) s += t;
    }
    if (l < nb) bsums[l] = s - v;
}

__global__ void scan_add(int* __restrict__ offs, int n_off,
                         const int* __restrict__ bsums) {
    int gid = blockIdx.x * 1024 + threadIdx.x;
    if (gid < n_off) offs[gid] += bsums[blockIdx.x];
}

__global__ void fill_csr(const int* __restrict__ ei, int E, int N,
                         const int* __restrict__ offs, int* __restrict__ fil,
                         int* __restrict__ csr) {
    int e = blockIdx.x * 256 + threadIdx.x;
    int ET = E + N;
    if (e >= ET) return;
    int src, dst;
    if (e < E) { src = ei[e]; dst = ei[E + e]; }
    else       { src = dst = e - E; }
    int pos = offs[dst] + atomicAdd(&fil[dst], 1);
    csr[pos] = src;
}

// ---------------- tiny converters ----------------
// W [K,N] f32 -> Wt [N,K] fp16
__global__ void wcast_t(const float* __restrict__ W, int K, int N,
                        _Float16* __restrict__ o) {
    int idx = blockIdx.x * 256 + threadIdx.x;
    if (idx >= N * K) return;
    int n = idx / K, k = idx - n * K;
    o[idx] = (_Float16)W[(size_t)k * N + n];
}

// x f32 -> fp16 (flat, 4 elems/thread)
__global__ void xcast(const float* __restrict__ x, _Float16* __restrict__ o,
                      int n4) {
    int i = blockIdx.x * 256 + threadIdx.x;
    if (i >= n4) return;
    float4 v = ((const float4*)x)[i];
    half4v h = {(_Float16)v.x, (_Float16)v.y, (_Float16)v.z, (_Float16)v.w};
    ((half4v*)o)[i] = h;
}

// ---------------- fp16 MFMA GEMM: C[M,N] = A[M,K] @ B[K,N] -----------------
// A fp16 [M,K] row-major. Bt fp16 [N,K]. C fp16.
// BM=128 BN=128 BK=32; 4 waves 2x2; wave tile 64x64 = 4x4 16x16x32 MFMA.
// ALMODE: 1=per-wave head sum (H=4); 2=block LDS reduce (H=1, grid.x==1).
template <int ALMODE>
__global__ __launch_bounds__(256) void gemm_f16(
    const _Float16* __restrict__ A, const _Float16* __restrict__ Bt,
    _Float16* __restrict__ C,
    const float* __restrict__ a_s, const float* __restrict__ a_d,
    float* __restrict__ als, float* __restrict__ ald,
    int M, int N, int K) {
    __shared__ _Float16 As[128][40], Bs[128][40];  // +8 pad, 20 KB total
    __shared__ float s_als[128], s_ald[128];
    const int bm = blockIdx.y * 128, bn = blockIdx.x * 128;
    const int tid = threadIdx.x;
    const int w = tid >> 6, lane = tid & 63;
    const int wm = (w >> 1) * 64, wn = (w & 1) * 64;
    const int l16 = lane & 15, q = lane >> 4;
    const int kq = q * 8;
    const int sr = tid >> 1;          // staging row 0..127
    const int sk = (tid & 1) * 16;    // staging k-offset 0/16 (halves)

    f32x4 acc[4][4];
#pragma unroll
    for (int i = 0; i < 4; ++i)
#pragma unroll
        for (int j = 0; j < 4; ++j) acc[i][j] = (f32x4){0.f, 0.f, 0.f, 0.f};

    for (int k0 = 0; k0 < K; k0 += 32) {
        {
            int row = bm + sr;
            uint4 v0, v1;
            if (row < M) {
                const uint4* ap = (const uint4*)(A + (size_t)row * K + k0 + sk);
                v0 = ap[0]; v1 = ap[1];
            } else {
                v0 = make_uint4(0u, 0u, 0u, 0u); v1 = v0;
            }
            *(uint4*)&As[sr][sk]     = v0;
            *(uint4*)&As[sr][sk + 8] = v1;
            const uint4* bp = (const uint4*)(Bt + (size_t)(bn + sr) * K + k0 + sk);
            *(uint4*)&Bs[sr][sk]     = bp[0];
            *(uint4*)&Bs[sr][sk + 8] = bp[1];
        }
        __syncthreads();
        half8 a[4], b[4];
#pragma unroll
        for (int t = 0; t < 4; ++t) {
            a[t] = *(const half8*)&As[wm + t * 16 + l16][kq];
            b[t] = *(const half8*)&Bs[wn + t * 16 + l16][kq];
        }
#pragma unroll
        for (int i = 0; i < 4; ++i)
#pragma unroll
            for (int j = 0; j < 4; ++j)
                acc[i][j] = __builtin_amdgcn_mfma_f32_16x16x32_f16(
                    a[i], b[j], acc[i][j], 0, 0, 0);
        __syncthreads();
    }

    if constexpr (ALMODE == 2) {
        if (tid < 128) { s_als[tid] = 0.f; s_ald[tid] = 0.f; }
        __syncthreads();
    }
    // epilogue: C/D layout col = lane&15, row = q*4 + reg
#pragma unroll
    for (int i = 0; i < 4; ++i) {
#pragma unroll
        for (int r = 0; r < 4; ++r) {
            int row = bm + wm + i * 16 + q * 4 + r;
            float c0 = acc[i][0][r], c1 = acc[i][1][r];
            float c2 = acc[i][2][r], c3 = acc[i][3][r];
            if (row < M) {
                _Float16* cp = C + (size_t)row * N + bn + wn + l16;
                cp[0]  = (_Float16)c0;
                cp[16] = (_Float16)c1;
                cp[32] = (_Float16)c2;
                cp[48] = (_Float16)c3;
            }
            {
                const int cg = bn + wn + l16;
                float ps = c0 * a_s[cg] + c1 * a_s[cg + 16] +
                           c2 * a_s[cg + 32] + c3 * a_s[cg + 48];
                float pd = c0 * a_d[cg] + c1 * a_d[cg + 16] +
                           c2 * a_d[cg + 32] + c3 * a_d[cg + 48];
#pragma unroll
                for (int o = 1; o < 16; o <<= 1) {
                    ps += __shfl_xor(ps, o, 64);
                    pd += __shfl_xor(pd, o, 64);
                }
                if constexpr (ALMODE == 1) {
                    if (l16 == 0 && row < M) {
                        const int head = (bn + wn) >> 6;
                        als[row * 4 + head] = ps;
                        ald[row * 4 + head] = pd;
                    }
                } else {
                    if (l16 == 0) {
                        atomicAdd(&s_als[wm + i * 16 + q * 4 + r], ps);
                        atomicAdd(&s_ald[wm + i * 16 + q * 4 + r], pd);
                    }
                }
            }
        }
    }
    if constexpr (ALMODE == 2) {
        __syncthreads();
        if (tid < 128) {
            int row = bm + tid;
            if (row < M) { als[row] = s_als[tid]; ald[row] = s_ald[tid]; }
        }
    }
}

// ---------------- aggregation H=4 C=64: fp16 h gather, fp16 out ------------
template <bool ACT>
__global__ __launch_bounds__(256) void aggregate_h4_f16(
    const _Float16* __restrict__ h, const float4* __restrict__ als4,
    const float4* __restrict__ ald4, const int* __restrict__ offs,
    const int* __restrict__ csr, const float* __restrict__ bias,
    _Float16* __restrict__ out, int Nn) {
    const int tid = threadIdx.x;
    const int w = tid >> 6;
    const int l = tid & 63;
    const int n = blockIdx.x * 4 + w;
    __shared__ float s_alpha[4][64][4];
    __shared__ int s_src[4][64];
    if (n >= Nn) return;

    const int base = offs[n];
    const int deg = offs[n + 1] - base;
    const float4 adv = ald4[n];

    const bool has0 = (l < deg);
    int src0 = 0;
    float4 sc0 = make_float4(-1e30f, -1e30f, -1e30f, -1e30f);
    if (has0) {
        src0 = csr[base + l];
        float4 a = als4[src0];
        sc0 = lrelu4(make_float4(a.x + adv.x, a.y + adv.y, a.z + adv.z, a.w + adv.w));
    }
    float4 m = sc0;
    for (int i = l + 64; i < deg; i += 64) {
        int s = csr[base + i];
        float4 a = als4[s];
        float4 sc = lrelu4(make_float4(a.x + adv.x, a.y + adv.y, a.z + adv.z, a.w + adv.w));
        m.x = fmaxf(m.x, sc.x); m.y = fmaxf(m.y, sc.y);
        m.z = fmaxf(m.z, sc.z); m.w = fmaxf(m.w, sc.w);
    }
    m.x = wave_allred_max(m.x); m.y = wave_allred_max(m.y);
    m.z = wave_allred_max(m.z); m.w = wave_allred_max(m.w);

    float4 ssum = make_float4(0.f, 0.f, 0.f, 0.f);
    if (has0) {
        float4 ex = make_float4(__expf(sc0.x - m.x), __expf(sc0.y - m.y),
                                __expf(sc0.z - m.z), __expf(sc0.w - m.w));
        *(float4*)&s_alpha[w][l][0] = ex;
        s_src[w][l] = src0;
        ssum = ex;
    }
    for (int i = l + 64; i < deg; i += 64) {
        int s = csr[base + i];
        float4 a = als4[s];
        float4 sc = lrelu4(make_float4(a.x + adv.x, a.y + adv.y, a.z + adv.z, a.w + adv.w));
        ssum.x += __expf(sc.x - m.x); ssum.y += __expf(sc.y - m.y);
        ssum.z += __expf(sc.z - m.z); ssum.w += __expf(sc.w - m.w);
    }
    ssum.x = wave_allred_sum(ssum.x); ssum.y = wave_allred_sum(ssum.y);
    ssum.z = wave_allred_sum(ssum.z); ssum.w = wave_allred_sum(ssum.w);

    const int head = l >> 4;
    float rc;
    {
        float d = (head == 0) ? ssum.x : (head == 1) ? ssum.y
                 : (head == 2) ? ssum.z : ssum.w;
        rc = 1.f / (d + EPS_SM);
    }

    float4 acc = make_float4(0.f, 0.f, 0.f, 0.f);
    for (int c0 = 0; c0 < deg; c0 += 64) {
        const int cl = min(64, deg - c0);
        if (c0 > 0) {
            if (l < cl) {
                int s = csr[base + c0 + l];
                float4 a = als4[s];
                float4 sc = lrelu4(make_float4(a.x + adv.x, a.y + adv.y,
                                               a.z + adv.z, a.w + adv.w));
                s_alpha[w][l][0] = __expf(sc.x - m.x);
                s_alpha[w][l][1] = __expf(sc.y - m.y);
                s_alpha[w][l][2] = __expf(sc.z - m.z);
                s_alpha[w][l][3] = __expf(sc.w - m.w);
                s_src[w][l] = s;
            }
        }
        int e = 0;
        for (; e + 4 <= cl; e += 4) {
            int s0 = s_src[w][e + 0], s1 = s_src[w][e + 1];
            int s2 = s_src[w][e + 2], s3 = s_src[w][e + 3];
            float a0 = s_alpha[w][e + 0][head];
            float a1 = s_alpha[w][e + 1][head];
            float a2 = s_alpha[w][e + 2][head];
            float a3 = s_alpha[w][e + 3][head];
            half4v hv0 = *(const half4v*)(h + (size_t)s0 * 256 + l * 4);
            half4v hv1 = *(const half4v*)(h + (size_t)s1 * 256 + l * 4);
            half4v hv2 = *(const half4v*)(h + (size_t)s2 * 256 + l * 4);
            half4v hv3 = *(const half4v*)(h + (size_t)s3 * 256 + l * 4);
            acc.x = fmaf(a0, (float)hv0[0], acc.x);
            acc.y = fmaf(a0, (float)hv0[1], acc.y);
            acc.z = fmaf(a0, (float)hv0[2], acc.z);
            acc.w = fmaf(a0, (float)hv0[3], acc.w);
            acc.x = fmaf(a1, (float)hv1[0], acc.x);
            acc.y = fmaf(a1, (float)hv1[1], acc.y);
            acc.z = fmaf(a1, (float)hv1[2], acc.z);
            acc.w = fmaf(a1, (float)hv1[3], acc.w);
            acc.x = fmaf(a2, (float)hv2[0], acc.x);
            acc.y = fmaf(a2, (float)hv2[1], acc.y);
            acc.z = fmaf(a2, (float)hv2[2], acc.z);
            acc.w = fmaf(a2, (float)hv2[3], acc.w);
            acc.x = fmaf(a3, (float)hv3[0], acc.x);
            acc.y = fmaf(a3, (float)hv3[1], acc.y);
            acc.z = fmaf(a3, (float)hv3[2], acc.z);
            acc.w = fmaf(a3, (float)hv3[3], acc.w);
        }
        for (; e < cl; ++e) {
            int s0 = s_src[w][e];
            float a0 = s_alpha[w][e][head];
            half4v hv0 = *(const half4v*)(h + (size_t)s0 * 256 + l * 4);
            acc.x = fmaf(a0, (float)hv0[0], acc.x);
            acc.y = fmaf(a0, (float)hv0[1], acc.y);
            acc.z = fmaf(a0, (float)hv0[2], acc.z);
            acc.w = fmaf(a0, (float)hv0[3], acc.w);
        }
    }
    float4 bv = *(const float4*)(bias + l * 4);
    float4 r = make_float4(acc.x * rc + bv.x, acc.y * rc + bv.y,
                           acc.z * rc + bv.z, acc.w * rc + bv.w);
    if (ACT) {
        r.x = (r.x > 0.f) ? r.x : expm1f(r.x);
        r.y = (r.y > 0.f) ? r.y : expm1f(r.y);
        r.z = (r.z > 0.f) ? r.z : expm1f(r.z);
        r.w = (r.w > 0.f) ? r.w : expm1f(r.w);
    }
    half4v ov = {(_Float16)r.x, (_Float16)r.y, (_Float16)r.z, (_Float16)r.w};
    *(half4v*)(out + (size_t)n * 256 + l * 4) = ov;
}

// ---------------- aggregation H=1 C=128 (fp16 h, f32 out) ------------------
__global__ __launch_bounds__(256) void aggregate_h1_f16(
    const _Float16* __restrict__ h, const float* __restrict__ als,
    const float* __restrict__ ald, const int* __restrict__ offs,
    const int* __restrict__ csr, const float* __restrict__ bias,
    float* __restrict__ out, int Nn) {
    const int tid = threadIdx.x;
    const int w = tid >> 6;
    const int l = tid & 63;
    const int n = blockIdx.x * 4 + w;
    __shared__ float s_alpha[4][64];
    __shared__ int s_src[4][64];
    if (n >= Nn) return;

    const int base = offs[n];
    const int deg = offs[n + 1] - base;
    const float ad_n = ald[n];

    const bool has0 = (l < deg);
    int src0 = 0;
    float sc0 = -1e30f;
    if (has0) {
        src0 = csr[base + l];
        float sc = als[src0] + ad_n;
        sc0 = (sc < 0.f) ? NEG_SLOPE * sc : sc;
    }
    float m = sc0;
    for (int i = l + 64; i < deg; i += 64) {
        int s = csr[base + i];
        float sc = als[s] + ad_n;
        sc = (sc < 0.f) ? NEG_SLOPE * sc : sc;
        m = fmaxf(m, sc);
    }
    m = wave_allred_max(m);

    float ssum = 0.f;
    if (has0) {
        float ex = __expf(sc0 - m);
        s_alpha[w][l] = ex;
        s_src[w][l] = src0;
        ssum = ex;
    }
    for (int i = l + 64; i < deg; i += 64) {
        int s = csr[base + i];
        float sc = als[s] + ad_n;
        sc = (sc < 0.f) ? NEG_SLOPE * sc : sc;
        ssum += __expf(sc - m);
    }
    ssum = wave_allred_sum(ssum);
    const float rc = 1.f / (ssum + EPS_SM);

    float2 acc = make_float2(0.f, 0.f);
    for (int c0 = 0; c0 < deg; c0 += 64) {
        const int cl = min(64, deg - c0);
        if (c0 > 0) {
            if (l < cl) {
                int s = csr[base + c0 + l];
                float sc = als[s] + ad_n;
                sc = (sc < 0.f) ? NEG_SLOPE * sc : sc;
                s_alpha[w][l] = __expf(sc - m);
                s_src[w][l] = s;
            }
        }
        int e = 0;
        for (; e + 4 <= cl; e += 4) {
            int s0 = s_src[w][e + 0], s1 = s_src[w][e + 1];
            int s2 = s_src[w][e + 2], s3 = s_src[w][e + 3];
            float a0 = s_alpha[w][e + 0], a1 = s_alpha[w][e + 1];
            float a2 = s_alpha[w][e + 2], a3 = s_alpha[w][e + 3];
            half2v v0 = *(const half2v*)(h + (size_t)s0 * 128 + l * 2);
            half2v v1 = *(const half2v*)(h + (size_t)s1 * 128 + l * 2);
            half2v v2 = *(const half2v*)(h + (size_t)s2 * 128 + l * 2);
            half2v v3 = *(const half2v*)(h + (size_t)s3 * 128 + l * 2);
            acc.x = fmaf(a0, (float)v0[0], acc.x); acc.y = fmaf(a0, (float)v0[1], acc.y);
            acc.x = fmaf(a1, (float)v1[0], acc.x); acc.y = fmaf(a1, (float)v1[1], acc.y);
            acc.x = fmaf(a2, (float)v2[0], acc.x); acc.y = fmaf(a2, (float)v2[1], acc.y);
            acc.x = fmaf(a3, (float)v3[0], acc.x); acc.y = fmaf(a3, (float)v3[1], acc.y);
        }
        for (; e < cl; ++e) {
            int s0 = s_src[w][e];
            float a0 = s_alpha[w][e];
            half2v v0 = *(const half2v*)(h + (size_t)s0 * 128 + l * 2);
            acc.x = fmaf(a0, (float)v0[0], acc.x); acc.y = fmaf(a0, (float)v0[1], acc.y);
        }
    }
    float2 r = make_float2(acc.x * rc + bias[l * 2],
                           acc.y * rc + bias[l * 2 + 1]);
    *(float2*)(out + (size_t)n * 128 + l * 2) = r;
}

// ---------------------------------------------------------------------------
extern "C" void kernel_launch(void* const* d_in, const int* in_sizes, int n_in,
                              void* d_out, int out_size, void* d_ws,
                              size_t ws_size, hipStream_t stream) {
    const float* x   = (const float*)d_in[0];
    const int*   ei  = (const int*)d_in[1];
    const float* W1  = (const float*)d_in[2];
    const float* as1 = (const float*)d_in[3];
    const float* ad1 = (const float*)d_in[4];
    const float* b1  = (const float*)d_in[5];
    const float* W2  = (const float*)d_in[6];
    const float* as2 = (const float*)d_in[7];
    const float* ad2 = (const float*)d_in[8];
    const float* b2  = (const float*)d_in[9];
    const float* W3  = (const float*)d_in[10];
    const float* as3 = (const float*)d_in[11];
    const float* ad3 = (const float*)d_in[12];
    const float* b3  = (const float*)d_in[13];

    const int Nn = in_sizes[0] / 256;   // 50000 nodes
    const int E  = in_sizes[1] / 2;     // 800000 edges
    const int ET = E + Nn;

    // workspace carve
    char* p = (char*)d_ws;
    _Float16* bufA = (_Float16*)p; p += (size_t)Nn * 256 * 2;  // fp16 features
    _Float16* bufB = (_Float16*)p; p += (size_t)Nn * 256 * 2;  // fp16 features
    float* als  = (float*)p; p += (size_t)Nn * 4 * 4;
    float* ald  = (float*)p; p += (size_t)Nn * 4 * 4;
    int* cnt  = (int*)p; p += (size_t)Nn * 4;
    int* fil  = (int*)p; p += (size_t)Nn * 4;
    int* offs = (int*)p; p += (size_t)(Nn + 1) * 4;
    int* bsums = (int*)p; p += 256 * 4;
    int* csr  = (int*)p; p += (size_t)ET * 4;
    p = (char*)(((uintptr_t)p + 15) & ~(uintptr_t)15);
    _Float16* wt1 = (_Float16*)p; p += 256 * 256 * 2;
    _Float16* wt2 = (_Float16*)p; p += 256 * 256 * 2;
    _Float16* wt3 = (_Float16*)p; p += 128 * 256 * 2;

    // --- CSR build + casts ---
    hipMemsetAsync(cnt, 0, (size_t)2 * Nn * sizeof(int), stream);
    int nbE = (ET + 255) / 256;
    hist_kernel<<<nbE, 256, 0, stream>>>(ei, E, Nn, cnt);
    wcast_t<<<(256 * 256 + 255) / 256, 256, 0, stream>>>(W1, 256, 256, wt1);
    wcast_t<<<(256 * 256 + 255) / 256, 256, 0, stream>>>(W2, 256, 256, wt2);
    wcast_t<<<(128 * 256 + 255) / 256, 256, 0, stream>>>(W3, 256, 128, wt3);
    xcast<<<(Nn * 64 + 255) / 256, 256, 0, stream>>>(x, bufA, Nn * 64);
    int nbS = (Nn + 1 + 1023) / 1024;
    scan_block<<<nbS, 1024, 0, stream>>>(cnt, Nn, offs, Nn + 1, bsums);
    scan_sums<<<1, 64, 0, stream>>>(bsums, nbS);
    scan_add<<<nbS, 1024, 0, stream>>>(offs, Nn + 1, bsums);
    fill_csr<<<nbE, 256, 0, stream>>>(ei, E, Nn, offs, fil, csr);

    const int gm = (Nn + 127) / 128;   // 391
    const int ga = (Nn + 3) / 4;       // 12500

    // --- layer 1: 256 -> 256, H=4, C=64, ELU ---
    gemm_f16<1><<<dim3(2, gm), 256, 0, stream>>>(
        bufA, wt1, bufB, as1, ad1, als, ald, Nn, 256, 256);
    aggregate_h4_f16<true><<<ga, 256, 0, stream>>>(
        bufB, (const float4*)als, (const float4*)ald, offs, csr, b1, bufA, Nn);

    // --- layer 2: 256 -> 256, H=4, C=64, ELU ---
    gemm_f16<1><<<dim3(2, gm), 256, 0, stream>>>(
        bufA, wt2, bufB, as2, ad2, als, ald, Nn, 256, 256);
    aggregate_h4_f16<true><<<ga, 256, 0, stream>>>(
        bufB, (const float4*)als, (const float4*)ald, offs, csr, b2, bufA, Nn);

    // --- layer 3: 256 -> 128, H=1, C=128, no act ---
    gemm_f16<2><<<dim3(1, gm), 256, 0, stream>>>(
        bufA, wt3, bufB, as3, ad3, als, ald, Nn, 128, 256);
    aggregate_h1_f16<<<ga, 256, 0, stream>>>(
        bufB, als, ald, offs, csr, b3, (float*)d_out, Nn);
}

// Round 6
// 435.019 us; speedup vs baseline: 1.1637x; 1.0501x over previous
//
#include <hip/hip_runtime.h>
#include <math.h>

// ---------------------------------------------------------------------------
// GAT 3-layer forward.
// R9: all-fp16 datapath, mfma_f32_16x16x32_f16 (457us, absmax unchanged).
// R10: (1) single-pass aggregation: no max-subtract pass (scores bounded,
//      exp-safe in f32), denom accumulated alongside weighted sum, divide
//      at end -> 1 edge scan instead of 3 (VALU cut ~2.5x).
//      (2) GEMM 2-phase double-buffered prefetch (reg-staged, 1 barrier/iter).
//      (3) xcast deleted (gemm1 converts f32 x in staging); wcast fused x3->1.
// ---------------------------------------------------------------------------

#define NEG_SLOPE 0.2f
#define EPS_SM 1e-16f

typedef _Float16 half8 __attribute__((ext_vector_type(8)));
typedef _Float16 half4v __attribute__((ext_vector_type(4)));
typedef _Float16 half2v __attribute__((ext_vector_type(2)));
typedef float f32x4 __attribute__((ext_vector_type(4)));

__device__ __forceinline__ float wave_allred_sum(float v) {
#pragma unroll
    for (int o = 32; o > 0; o >>= 1) v += __shfl_xor(v, o, 64);
    return v;
}
__device__ __forceinline__ float4 lrelu4(float4 v) {
    v.x = (v.x < 0.f) ? NEG_SLOPE * v.x : v.x;
    v.y = (v.y < 0.f) ? NEG_SLOPE * v.y : v.y;
    v.z = (v.z < 0.f) ? NEG_SLOPE * v.z : v.z;
    v.w = (v.w < 0.f) ? NEG_SLOPE * v.w : v.w;
    return v;
}

// ---------------- CSR build ----------------
__global__ void hist_kernel(const int* __restrict__ ei, int E, int N,
                            int* __restrict__ cnt) {
    int e = blockIdx.x * 256 + threadIdx.x;
    int ET = E + N;
    if (e >= ET) return;
    int dst = (e < E) ? ei[E + e] : (e - E);
    atomicAdd(&cnt[dst], 1);
}

__global__ void scan_block(const int* __restrict__ cnt, int n_cnt,
                           int* __restrict__ offs, int n_off,
                           int* __restrict__ bsums) {
    __shared__ int buf[1024];
    int gid = blockIdx.x * 1024 + threadIdx.x;
    int v = (gid < n_cnt) ? cnt[gid] : 0;
    buf[threadIdx.x] = v;
    __syncthreads();
#pragma unroll
    for (int off = 1; off < 1024; off <<= 1) {
        int t = (threadIdx.x >= off) ? buf[threadIdx.x - off] : 0;
        __syncthreads();
        buf[threadIdx.x] += t;
        __syncthreads();
    }
    if (gid < n_off) offs[gid] = buf[threadIdx.x] - v;
    if (threadIdx.x == 1023) bsums[blockIdx.x] = buf[1023];
}

// parallel exclusive scan of block sums (nb <= 64, one wave)
__global__ void scan_sums(int* __restrict__ bsums, int nb) {
    int l = threadIdx.x;
    int v = (l < nb) ? bsums[l] : 0;
    int s = v;
#pragma unroll
    for (int o = 1; o < 64; o <<= 1) {
        int t = __shfl_up(s, o, 64);
        if (l >= o) s += t;
    }
    if (l < nb) bsums[l] = s - v;
}

__global__ void scan_add(int* __restrict__ offs, int n_off,
                         const int* __restrict__ bsums) {
    int gid = blockIdx.x * 1024 + threadIdx.x;
    if (gid < n_off) offs[gid] += bsums[blockIdx.x];
}

__global__ void fill_csr(const int* __restrict__ ei, int E, int N,
                         const int* __restrict__ offs, int* __restrict__ fil,
                         int* __restrict__ csr) {
    int e = blockIdx.x * 256 + threadIdx.x;
    int ET = E + N;
    if (e >= ET) return;
    int src, dst;
    if (e < E) { src = ei[e]; dst = ei[E + e]; }
    else       { src = dst = e - E; }
    int pos = offs[dst] + atomicAdd(&fil[dst], 1);
    csr[pos] = src;
}

// ---------------- all W -> fp16 transposed, one kernel ----------------
__global__ void wcast_all(const float* __restrict__ W1,
                          const float* __restrict__ W2,
                          const float* __restrict__ W3,
                          _Float16* __restrict__ o1,
                          _Float16* __restrict__ o2,
                          _Float16* __restrict__ o3) {
    int i = blockIdx.x * 256 + threadIdx.x;  // 0 .. 163839
    const float* W; _Float16* o; int K = 256, N, s;
    if (i < 65536)        { W = W1; o = o1; N = 256; s = i; }
    else if (i < 131072)  { W = W2; o = o2; N = 256; s = i - 65536; }
    else if (i < 163840)  { W = W3; o = o3; N = 128; s = i - 131072; }
    else return;
    int n = s / K, k = s - n * K;
    o[s] = (_Float16)W[(size_t)k * N + n];
}

// ---------------- fp16 MFMA GEMM, 2-phase double-buffered ------------------
// C[M,N] = A[M,K] @ B[K,N]. A fp16 [M,K] (or f32 if AF32). Bt fp16 [N,K].
// BM=128 BN=128 BK=32; 4 waves 2x2; wave tile 64x64 = 4x4 16x16x32 MFMA.
// ALMODE: 1=per-wave head sum (H=4); 2=block LDS reduce (H=1, grid.x==1).
template <bool AF32, int ALMODE>
__global__ __launch_bounds__(256) void gemm_f16(
    const void* __restrict__ Ain, const _Float16* __restrict__ Bt,
    _Float16* __restrict__ C,
    const float* __restrict__ a_s, const float* __restrict__ a_d,
    float* __restrict__ als, float* __restrict__ ald,
    int M, int N, int K) {
    __shared__ _Float16 As[2][128][40], Bs[2][128][40];  // 40 KB
    __shared__ float s_als[128], s_ald[128];
    const int bm = blockIdx.y * 128, bn = blockIdx.x * 128;
    const int tid = threadIdx.x;
    const int w = tid >> 6, lane = tid & 63;
    const int wm = (w >> 1) * 64, wn = (w & 1) * 64;
    const int l16 = lane & 15, q = lane >> 4;
    const int kq = q * 8;
    const int sr = tid >> 1;          // staging row 0..127
    const int sk = (tid & 1) * 16;    // staging k-offset 0/16 (halves)
    const int row = bm + sr;
    const int NT = K >> 5;

    f32x4 acc[4][4];
#pragma unroll
    for (int i = 0; i < 4; ++i)
#pragma unroll
        for (int j = 0; j < 4; ++j) acc[i][j] = (f32x4){0.f, 0.f, 0.f, 0.f};

    half8 ra0, ra1, rb0, rb1;
    // ---- load tile kt into regs ----
    auto LOAD = [&](int kt) {
        if constexpr (AF32) {
            const float* Af = (const float*)Ain;
            float4 v0, v1, v2, v3;
            if (row < M) {
                const float4* ap = (const float4*)(Af + (size_t)row * K + kt + sk);
                v0 = ap[0]; v1 = ap[1]; v2 = ap[2]; v3 = ap[3];
            } else {
                v0 = v1 = v2 = v3 = make_float4(0.f, 0.f, 0.f, 0.f);
            }
            ra0[0] = (_Float16)v0.x; ra0[1] = (_Float16)v0.y;
            ra0[2] = (_Float16)v0.z; ra0[3] = (_Float16)v0.w;
            ra0[4] = (_Float16)v1.x; ra0[5] = (_Float16)v1.y;
            ra0[6] = (_Float16)v1.z; ra0[7] = (_Float16)v1.w;
            ra1[0] = (_Float16)v2.x; ra1[1] = (_Float16)v2.y;
            ra1[2] = (_Float16)v2.z; ra1[3] = (_Float16)v2.w;
            ra1[4] = (_Float16)v3.x; ra1[5] = (_Float16)v3.y;
            ra1[6] = (_Float16)v3.z; ra1[7] = (_Float16)v3.w;
        } else {
            const _Float16* Ah = (const _Float16*)Ain;
            if (row < M) {
                const half8* ap = (const half8*)(Ah + (size_t)row * K + kt + sk);
                ra0 = ap[0]; ra1 = ap[1];
            } else {
                ra0 = (half8)(_Float16)0; ra1 = (half8)(_Float16)0;
            }
        }
        const half8* bp = (const half8*)(Bt + (size_t)(bn + sr) * K + kt + sk);
        rb0 = bp[0]; rb1 = bp[1];
    };
    auto STORE = [&](int nb) {
        *(half8*)&As[nb][sr][sk]     = ra0;
        *(half8*)&As[nb][sr][sk + 8] = ra1;
        *(half8*)&Bs[nb][sr][sk]     = rb0;
        *(half8*)&Bs[nb][sr][sk + 8] = rb1;
    };

    LOAD(0);
    STORE(0);
    int cur = 0;
    for (int kb = 0; kb < NT; ++kb) {
        const bool more = (kb + 1) < NT;
        if (more) LOAD((kb + 1) * 32);       // prefetch next tile (global)
        __syncthreads();                      // buf[cur] ready
        half8 a[4], b[4];
#pragma unroll
        for (int t = 0; t < 4; ++t) {
            a[t] = *(const half8*)&As[cur][wm + t * 16 + l16][kq];
            b[t] = *(const half8*)&Bs[cur][wn + t * 16 + l16][kq];
        }
#pragma unroll
        for (int i = 0; i < 4; ++i)
#pragma unroll
            for (int j = 0; j < 4; ++j)
                acc[i][j] = __builtin_amdgcn_mfma_f32_16x16x32_f16(
                    a[i], b[j], acc[i][j], 0, 0, 0);
        if (more) STORE(cur ^ 1);             // write-late (after barrier)
        cur ^= 1;
    }

    if constexpr (ALMODE == 2) {
        __syncthreads();
        if (tid < 128) { s_als[tid] = 0.f; s_ald[tid] = 0.f; }
        __syncthreads();
    }
    // epilogue: C/D layout col = lane&15, row = q*4 + reg
#pragma unroll
    for (int i = 0; i < 4; ++i) {
#pragma unroll
        for (int r = 0; r < 4; ++r) {
            int orow = bm + wm + i * 16 + q * 4 + r;
            float c0 = acc[i][0][r], c1 = acc[i][1][r];
            float c2 = acc[i][2][r], c3 = acc[i][3][r];
            if (orow < M) {
                _Float16* cp = C + (size_t)orow * N + bn + wn + l16;
                cp[0]  = (_Float16)c0;
                cp[16] = (_Float16)c1;
                cp[32] = (_Float16)c2;
                cp[48] = (_Float16)c3;
            }
            {
                const int cg = bn + wn + l16;
                float ps = c0 * a_s[cg] + c1 * a_s[cg + 16] +
                           c2 * a_s[cg + 32] + c3 * a_s[cg + 48];
                float pd = c0 * a_d[cg] + c1 * a_d[cg + 16] +
                           c2 * a_d[cg + 32] + c3 * a_d[cg + 48];
#pragma unroll
                for (int o = 1; o < 16; o <<= 1) {
                    ps += __shfl_xor(ps, o, 64);
                    pd += __shfl_xor(pd, o, 64);
                }
                if constexpr (ALMODE == 1) {
                    if (l16 == 0 && orow < M) {
                        const int head = (bn + wn) >> 6;
                        als[orow * 4 + head] = ps;
                        ald[orow * 4 + head] = pd;
                    }
                } else {
                    if (l16 == 0) {
                        atomicAdd(&s_als[wm + i * 16 + q * 4 + r], ps);
                        atomicAdd(&s_ald[wm + i * 16 + q * 4 + r], pd);
                    }
                }
            }
        }
    }
    if constexpr (ALMODE == 2) {
        __syncthreads();
        if (tid < 128) {
            int orow = bm + tid;
            if (orow < M) { als[orow] = s_als[tid]; ald[orow] = s_ald[tid]; }
        }
    }
}

// ---------------- aggregation H=4 C=64: single-pass, fp16 gather -----------
// No max subtraction (scores bounded << 80, f32 exp safe); denominator
// accumulated alongside weighted sum; divide once at the end.
template <bool ACT>
__global__ __launch_bounds__(256) void aggregate_h4_f16(
    const _Float16* __restrict__ h, const float4* __restrict__ als4,
    const float4* __restrict__ ald4, const int* __restrict__ offs,
    const int* __restrict__ csr, const float* __restrict__ bias,
    _Float16* __restrict__ out, int Nn) {
    const int tid = threadIdx.x;
    const int w = tid >> 6;
    const int l = tid & 63;
    const int n = blockIdx.x * 4 + w;
    __shared__ float s_alpha[4][64][4];
    __shared__ int s_src[4][64];
    if (n >= Nn) return;

    const int base = offs[n];
    const int deg = offs[n + 1] - base;
    const float4 adv = ald4[n];
    const int head = l >> 4;

    float4 acc = make_float4(0.f, 0.f, 0.f, 0.f);
    float4 den = make_float4(0.f, 0.f, 0.f, 0.f);
    for (int c0 = 0; c0 < deg; c0 += 64) {
        const int cl = min(64, deg - c0);
        if (l < cl) {
            int s = csr[base + c0 + l];
            float4 a = als4[s];
            float4 sc = lrelu4(make_float4(a.x + adv.x, a.y + adv.y,
                                           a.z + adv.z, a.w + adv.w));
            float4 ex = make_float4(__expf(sc.x), __expf(sc.y),
                                    __expf(sc.z), __expf(sc.w));
            *(float4*)&s_alpha[w][l][0] = ex;
            s_src[w][l] = s;
            den.x += ex.x; den.y += ex.y; den.z += ex.z; den.w += ex.w;
        }
        int e = 0;
        for (; e + 4 <= cl; e += 4) {
            int s0 = s_src[w][e + 0], s1 = s_src[w][e + 1];
            int s2 = s_src[w][e + 2], s3 = s_src[w][e + 3];
            float a0 = s_alpha[w][e + 0][head];
            float a1 = s_alpha[w][e + 1][head];
            float a2 = s_alpha[w][e + 2][head];
            float a3 = s_alpha[w][e + 3][head];
            half4v hv0 = *(const half4v*)(h + (size_t)s0 * 256 + l * 4);
            half4v hv1 = *(const half4v*)(h + (size_t)s1 * 256 + l * 4);
            half4v hv2 = *(const half4v*)(h + (size_t)s2 * 256 + l * 4);
            half4v hv3 = *(const half4v*)(h + (size_t)s3 * 256 + l * 4);
            acc.x = fmaf(a0, (float)hv0[0], acc.x);
            acc.y = fmaf(a0, (float)hv0[1], acc.y);
            acc.z = fmaf(a0, (float)hv0[2], acc.z);
            acc.w = fmaf(a0, (float)hv0[3], acc.w);
            acc.x = fmaf(a1, (float)hv1[0], acc.x);
            acc.y = fmaf(a1, (float)hv1[1], acc.y);
            acc.z = fmaf(a1, (float)hv1[2], acc.z);
            acc.w = fmaf(a1, (float)hv1[3], acc.w);
            acc.x = fmaf(a2, (float)hv2[0], acc.x);
            acc.y = fmaf(a2, (float)hv2[1], acc.y);
            acc.z = fmaf(a2, (float)hv2[2], acc.z);
            acc.w = fmaf(a2, (float)hv2[3], acc.w);
            acc.x = fmaf(a3, (float)hv3[0], acc.x);
            acc.y = fmaf(a3, (float)hv3[1], acc.y);
            acc.z = fmaf(a3, (float)hv3[2], acc.z);
            acc.w = fmaf(a3, (float)hv3[3], acc.w);
        }
        for (; e < cl; ++e) {
            int s0 = s_src[w][e];
            float a0 = s_alpha[w][e][head];
            half4v hv0 = *(const half4v*)(h + (size_t)s0 * 256 + l * 4);
            acc.x = fmaf(a0, (float)hv0[0], acc.x);
            acc.y = fmaf(a0, (float)hv0[1], acc.y);
            acc.z = fmaf(a0, (float)hv0[2], acc.z);
            acc.w = fmaf(a0, (float)hv0[3], acc.w);
        }
    }
    den.x = wave_allred_sum(den.x); den.y = wave_allred_sum(den.y);
    den.z = wave_allred_sum(den.z); den.w = wave_allred_sum(den.w);
    float d = (head == 0) ? den.x : (head == 1) ? den.y
             : (head == 2) ? den.z : den.w;
    const float rc = 1.f / (d + EPS_SM);

    float4 bv = *(const float4*)(bias + l * 4);
    float4 r = make_float4(acc.x * rc + bv.x, acc.y * rc + bv.y,
                           acc.z * rc + bv.z, acc.w * rc + bv.w);
    if (ACT) {
        r.x = (r.x > 0.f) ? r.x : expm1f(r.x);
        r.y = (r.y > 0.f) ? r.y : expm1f(r.y);
        r.z = (r.z > 0.f) ? r.z : expm1f(r.z);
        r.w = (r.w > 0.f) ? r.w : expm1f(r.w);
    }
    half4v ov = {(_Float16)r.x, (_Float16)r.y, (_Float16)r.z, (_Float16)r.w};
    *(half4v*)(out + (size_t)n * 256 + l * 4) = ov;
}

// ---------------- aggregation H=1 C=128: single-pass, fp16 h, f32 out ------
__global__ __launch_bounds__(256) void aggregate_h1_f16(
    const _Float16* __restrict__ h, const float* __restrict__ als,
    const float* __restrict__ ald, const int* __restrict__ offs,
    const int* __restrict__ csr, const float* __restrict__ bias,
    float* __restrict__ out, int Nn) {
    const int tid = threadIdx.x;
    const int w = tid >> 6;
    const int l = tid & 63;
    const int n = blockIdx.x * 4 + w;
    __shared__ float s_alpha[4][64];
    __shared__ int s_src[4][64];
    if (n >= Nn) return;

    const int base = offs[n];
    const int deg = offs[n + 1] - base;
    const float ad_n = ald[n];

    float2 acc = make_float2(0.f, 0.f);
    float den = 0.f;
    for (int c0 = 0; c0 < deg; c0 += 64) {
        const int cl = min(64, deg - c0);
        if (l < cl) {
            int s = csr[base + c0 + l];
            float sc = als[s] + ad_n;
            sc = (sc < 0.f) ? NEG_SLOPE * sc : sc;
            float ex = __expf(sc);
            s_alpha[w][l] = ex;
            s_src[w][l] = s;
            den += ex;
        }
        int e = 0;
        for (; e + 4 <= cl; e += 4) {
            int s0 = s_src[w][e + 0], s1 = s_src[w][e + 1];
            int s2 = s_src[w][e + 2], s3 = s_src[w][e + 3];
            float a0 = s_alpha[w][e + 0], a1 = s_alpha[w][e + 1];
            float a2 = s_alpha[w][e + 2], a3 = s_alpha[w][e + 3];
            half2v v0 = *(const half2v*)(h + (size_t)s0 * 128 + l * 2);
            half2v v1 = *(const half2v*)(h + (size_t)s1 * 128 + l * 2);
            half2v v2 = *(const half2v*)(h + (size_t)s2 * 128 + l * 2);
            half2v v3 = *(const half2v*)(h + (size_t)s3 * 128 + l * 2);
            acc.x = fmaf(a0, (float)v0[0], acc.x); acc.y = fmaf(a0, (float)v0[1], acc.y);
            acc.x = fmaf(a1, (float)v1[0], acc.x); acc.y = fmaf(a1, (float)v1[1], acc.y);
            acc.x = fmaf(a2, (float)v2[0], acc.x); acc.y = fmaf(a2, (float)v2[1], acc.y);
            acc.x = fmaf(a3, (float)v3[0], acc.x); acc.y = fmaf(a3, (float)v3[1], acc.y);
        }
        for (; e < cl; ++e) {
            int s0 = s_src[w][e];
            float a0 = s_alpha[w][e];
            half2v v0 = *(const half2v*)(h + (size_t)s0 * 128 + l * 2);
            acc.x = fmaf(a0, (float)v0[0], acc.x); acc.y = fmaf(a0, (float)v0[1], acc.y);
        }
    }
    den = wave_allred_sum(den);
    const float rc = 1.f / (den + EPS_SM);
    float2 r = make_float2(acc.x * rc + bias[l * 2],
                           acc.y * rc + bias[l * 2 + 1]);
    *(float2*)(out + (size_t)n * 128 + l * 2) = r;
}

// ---------------------------------------------------------------------------
extern "C" void kernel_launch(void* const* d_in, const int* in_sizes, int n_in,
                              void* d_out, int out_size, void* d_ws,
                              size_t ws_size, hipStream_t stream) {
    const float* x   = (const float*)d_in[0];
    const int*   ei  = (const int*)d_in[1];
    const float* W1  = (const float*)d_in[2];
    const float* as1 = (const float*)d_in[3];
    const float* ad1 = (const float*)d_in[4];
    const float* b1  = (const float*)d_in[5];
    const float* W2  = (const float*)d_in[6];
    const float* as2 = (const float*)d_in[7];
    const float* ad2 = (const float*)d_in[8];
    const float* b2  = (const float*)d_in[9];
    const float* W3  = (const float*)d_in[10];
    const float* as3 = (const float*)d_in[11];
    const float* ad3 = (const float*)d_in[12];
    const float* b3  = (const float*)d_in[13];

    const int Nn = in_sizes[0] / 256;   // 50000 nodes
    const int E  = in_sizes[1] / 2;     // 800000 edges
    const int ET = E + Nn;

    // workspace carve
    char* p = (char*)d_ws;
    _Float16* bufA = (_Float16*)p; p += (size_t)Nn * 256 * 2;  // fp16 features
    _Float16* bufB = (_Float16*)p; p += (size_t)Nn * 256 * 2;  // fp16 features
    float* als  = (float*)p; p += (size_t)Nn * 4 * 4;
    float* ald  = (float*)p; p += (size_t)Nn * 4 * 4;
    int* cnt  = (int*)p; p += (size_t)Nn * 4;
    int* fil  = (int*)p; p += (size_t)Nn * 4;
    int* offs = (int*)p; p += (size_t)(Nn + 1) * 4;
    int* bsums = (int*)p; p += 256 * 4;
    int* csr  = (int*)p; p += (size_t)ET * 4;
    p = (char*)(((uintptr_t)p + 15) & ~(uintptr_t)15);
    _Float16* wt1 = (_Float16*)p; p += 256 * 256 * 2;
    _Float16* wt2 = (_Float16*)p; p += 256 * 256 * 2;
    _Float16* wt3 = (_Float16*)p; p += 128 * 256 * 2;

    // --- CSR build + weight casts ---
    hipMemsetAsync(cnt, 0, (size_t)2 * Nn * sizeof(int), stream);
    int nbE = (ET + 255) / 256;
    hist_kernel<<<nbE, 256, 0, stream>>>(ei, E, Nn, cnt);
    wcast_all<<<(163840 + 255) / 256, 256, 0, stream>>>(W1, W2, W3, wt1, wt2, wt3);
    int nbS = (Nn + 1 + 1023) / 1024;
    scan_block<<<nbS, 1024, 0, stream>>>(cnt, Nn, offs, Nn + 1, bsums);
    scan_sums<<<1, 64, 0, stream>>>(bsums, nbS);
    scan_add<<<nbS, 1024, 0, stream>>>(offs, Nn + 1, bsums);
    fill_csr<<<nbE, 256, 0, stream>>>(ei, E, Nn, offs, fil, csr);

    const int gm = (Nn + 127) / 128;   // 391
    const int ga = (Nn + 3) / 4;       // 12500

    // --- layer 1: 256 -> 256, H=4, C=64, ELU (A = f32 x, converted in-stage)
    gemm_f16<true, 1><<<dim3(2, gm), 256, 0, stream>>>(
        x, wt1, bufB, as1, ad1, als, ald, Nn, 256, 256);
    aggregate_h4_f16<true><<<ga, 256, 0, stream>>>(
        bufB, (const float4*)als, (const float4*)ald, offs, csr, b1, bufA, Nn);

    // --- layer 2: 256 -> 256, H=4, C=64, ELU ---
    gemm_f16<false, 1><<<dim3(2, gm), 256, 0, stream>>>(
        bufA, wt2, bufB, as2, ad2, als, ald, Nn, 256, 256);
    aggregate_h4_f16<true><<<ga, 256, 0, stream>>>(
        bufB, (const float4*)als, (const float4*)ald, offs, csr, b2, bufA, Nn);

    // --- layer 3: 256 -> 128, H=1, C=128, no act ---
    gemm_f16<false, 2><<<dim3(1, gm), 256, 0, stream>>>(
        bufA, wt3, bufB, as3, ad3, als, ald, Nn, 128, 256);
    aggregate_h1_f16<<<ga, 256, 0, stream>>>(
        bufB, als, ald, offs, csr, b3, (float*)d_out, Nn);
}